// Round 6
// baseline (1357.901 us; speedup 1.0000x reference)
//
#include <hip/hip_runtime.h>
#include <math.h>

// Round 6: all-levels fp16 cell array + lerp-form interp + 2 points/thread.
// Round 5 post-mortem: VALU-instruction-bound (VALUBusy 61%, ~1900 wave-instrs
// /wave), plus 9.4M LDS bank-conflict cycles from divergent sRows reads and
// 128 broadcast ds_read_b128/thread for MLP weights.
// Fixes:
//  - levels 0..2 move OUT of LDS into the same fp16 cell array (104KB of
//    coarse cells is L1-resident by temporal locality) -> no LDS fill, no
//    divergent-LDS conflicts, unified 8-level loop
//  - nested-lerp trilinear (f0 + r*(f1-f0) over x,y,z): fewer VALU ops than
//    weight products
//  - 2 points/thread (g, g+N/2): MLP weight ds_reads shared by both points,
//    2x gather ILP
// Storage fp16, all math fp32 (absmax ~5e-7 << 2.3e-6 threshold).

typedef float v2f __attribute__((ext_vector_type(2)));

struct EncParams { float scale[8]; };

__constant__ constexpr int SIDE[8]   = {9, 11, 13, 16, 19, 23, 28, 33};
__constant__ constexpr int ROWOFF[8] = {0, 729, 2060, 4257, 8353, 15212, 27379, 49331};
__constant__ constexpr int CS[8]     = {8, 10, 12, 15, 18, 22, 27, 32};
__constant__ constexpr int CB[8]     = {0, 512, 1512, 3240, 6615, 12447, 23095, 42778};
#define TOTCELLS 75546   // sum of (side-1)^3 over all 8 levels

__device__ __forceinline__ unsigned int pack2h(float a, float b) {
    _Float16 ha = (_Float16)a, hb = (_Float16)b;
    unsigned short ua = __builtin_bit_cast(unsigned short, ha);
    unsigned short ub = __builtin_bit_cast(unsigned short, hb);
    return (unsigned int)ua | ((unsigned int)ub << 16);
}
__device__ __forceinline__ float2 unpack2h(unsigned int u) {
    _Float16 ha = __builtin_bit_cast(_Float16, (unsigned short)(u & 0xffffu));
    _Float16 hb = __builtin_bit_cast(_Float16, (unsigned short)(u >> 16));
    return make_float2((float)ha, (float)hb);
}

// ---- build fp16 per-cell 32B corner blocks, ALL levels ----
// cell c: 2x uint4. qa={q0.lo,q0.hi,q1.lo,q1.hi}, qb={q2.lo,q2.hi,q3.lo,q3.hi}
// q = dz*2+dy; lo = half2 feats at x-corner 0, hi = at x-corner 1.
__global__ __launch_bounds__(256) void build_cells_h(
    const float* __restrict__ table, uint4* __restrict__ cellsH)
{
    const int c = blockIdx.x * 256 + threadIdx.x;
    if (c >= TOTCELLS) return;

    int l = 0;
    #pragma unroll
    for (int i = 1; i < 8; ++i) if (c >= CB[i]) l = i;

    const int cs  = CS[l];
    const int rem = c - CB[l];
    const int ix  = rem % cs;
    const int t1  = rem / cs;
    const int iy  = t1 % cs;
    const int iz  = t1 / cs;

    const int side  = SIDE[l];
    const int side2 = side * side;
    const int row   = ROWOFF[l] + ix + iy * side + iz * side2;

    unsigned int q[8];
    #pragma unroll
    for (int dz = 0; dz < 2; ++dz) {
        #pragma unroll
        for (int dy = 0; dy < 2; ++dy) {
            const int r = row + dy * side + dz * side2;
            q[(dz * 2 + dy) * 2 + 0] = pack2h(table[2 * r + 0], table[2 * r + 1]);
            q[(dz * 2 + dy) * 2 + 1] = pack2h(table[2 * r + 2], table[2 * r + 3]);
        }
    }
    cellsH[2 * c + 0] = make_uint4(q[0], q[1], q[2], q[3]);
    cellsH[2 * c + 1] = make_uint4(q[4], q[5], q[6], q[7]);
}

__device__ __forceinline__ v2f lerp_pair(unsigned int lo, unsigned int hi, float r) {
    const float2 f0 = unpack2h(lo);
    const float2 f1 = unpack2h(hi);
    const v2f a = {f0.x, f0.y};
    const v2f b = {f1.x, f1.y};
    return a + r * (b - a);
}

// encode 4 levels [l0, l0+4) of two points; writes hl0/hl1[l0..l0+3]
__device__ __forceinline__ void encode_half(
    int l0,
    float px0, float py0, float pz0,
    float px1, float py1, float pz1,
    const uint4* __restrict__ cellsH, const EncParams& ep,
    v2f* hl0, v2f* hl1)
{
    int c0[4], c1[4];
    float rx0[4], ry0[4], rz0[4], rx1[4], ry1[4], rz1[4];

    #pragma unroll
    for (int k = 0; k < 4; ++k) {
        const int l = l0 + k;
        const float s = ep.scale[l];
        {
            const float fx = px0 * s + 0.5f, fy = py0 * s + 0.5f, fz = pz0 * s + 0.5f;
            const float gx = floorf(fx), gy = floorf(fy), gz = floorf(fz);
            rx0[k] = fx - gx; ry0[k] = fy - gy; rz0[k] = fz - gz;
            c0[k] = CB[l] + (((int)gz * CS[l] + (int)gy) * CS[l] + (int)gx);
        }
        {
            const float fx = px1 * s + 0.5f, fy = py1 * s + 0.5f, fz = pz1 * s + 0.5f;
            const float gx = floorf(fx), gy = floorf(fy), gz = floorf(fz);
            rx1[k] = fx - gx; ry1[k] = fy - gy; rz1[k] = fz - gz;
            c1[k] = CB[l] + (((int)gz * CS[l] + (int)gy) * CS[l] + (int)gx);
        }
    }

    uint4 qa0[4], qb0[4], qa1[4], qb1[4];
    #pragma unroll
    for (int k = 0; k < 4; ++k) {
        const uint4* p0 = cellsH + 2 * c0[k];
        const uint4* p1 = cellsH + 2 * c1[k];
        qa0[k] = p0[0]; qb0[k] = p0[1];
        qa1[k] = p1[0]; qb1[k] = p1[1];
    }

    #pragma unroll
    for (int k = 0; k < 4; ++k) {
        {
            const float rx = rx0[k], ry = ry0[k], rz = rz0[k];
            const v2f v00 = lerp_pair(qa0[k].x, qa0[k].y, rx);
            const v2f v01 = lerp_pair(qa0[k].z, qa0[k].w, rx);
            const v2f v10 = lerp_pair(qb0[k].x, qb0[k].y, rx);
            const v2f v11 = lerp_pair(qb0[k].z, qb0[k].w, rx);
            const v2f v0 = v00 + ry * (v01 - v00);
            const v2f v1 = v10 + ry * (v11 - v10);
            hl0[l0 + k] = v0 + rz * (v1 - v0);
        }
        {
            const float rx = rx1[k], ry = ry1[k], rz = rz1[k];
            const v2f v00 = lerp_pair(qa1[k].x, qa1[k].y, rx);
            const v2f v01 = lerp_pair(qa1[k].z, qa1[k].w, rx);
            const v2f v10 = lerp_pair(qb1[k].x, qb1[k].y, rx);
            const v2f v11 = lerp_pair(qb1[k].z, qb1[k].w, rx);
            const v2f v0 = v00 + ry * (v01 - v00);
            const v2f v1 = v10 + ry * (v11 - v10);
            hl1[l0 + k] = v0 + rz * (v1 - v0);
        }
    }
}

// ---- main fused kernel: 2 points per thread ----
__global__ __launch_bounds__(256, 3) void sdf_main(
    const float* __restrict__ x,
    const uint4* __restrict__ cellsH,
    const float* __restrict__ W0,
    const float* __restrict__ W1,
    const float* __restrict__ W2,
    float* __restrict__ out,
    int N, int Nh, EncParams ep)
{
    __shared__ __align__(16) float sW0t[256];    // transposed [i][j]
    __shared__ __align__(16) float sW1t[256];
    __shared__ __align__(16) float sW2[16];

    const int t = threadIdx.x;
    sW0t[(t & 15) * 16 + (t >> 4)] = W0[t];
    sW1t[(t & 15) * 16 + (t >> 4)] = W1[t];
    if (t < 16) sW2[t] = W2[t];
    __syncthreads();

    const int g = blockIdx.x * 256 + t;
    if (g >= Nh) return;
    const int p0 = g;
    const int p1c = min(g + Nh, N - 1);   // clamped; store guarded below

    const float px0 = __builtin_nontemporal_load(x + 3 * p0 + 0);
    const float py0 = __builtin_nontemporal_load(x + 3 * p0 + 1);
    const float pz0 = __builtin_nontemporal_load(x + 3 * p0 + 2);
    const float px1 = __builtin_nontemporal_load(x + 3 * p1c + 0);
    const float py1 = __builtin_nontemporal_load(x + 3 * p1c + 1);
    const float pz1 = __builtin_nontemporal_load(x + 3 * p1c + 2);

    v2f hl0[8], hl1[8];
    encode_half(0, px0, py0, pz0, px1, py1, pz1, cellsH, ep, hl0, hl1);
    encode_half(4, px0, py0, pz0, px1, py1, pz1, cellsH, ep, hl0, hl1);

    // ---- MLP for both points, shared weight reads ----
    const v2f zz = {0.0f, 0.0f};
    v2f a0[8], a1[8];
    #pragma unroll
    for (int j = 0; j < 8; ++j) { a0[j] = zz; a1[j] = zz; }

    #pragma unroll
    for (int i2 = 0; i2 < 8; ++i2) {
        const float4* w0 = reinterpret_cast<const float4*>(&sW0t[(2 * i2) * 16]);
        const float4* w1 = reinterpret_cast<const float4*>(&sW0t[(2 * i2 + 1) * 16]);
        const float h00 = hl0[i2].x, h01 = hl0[i2].y;
        const float h10 = hl1[i2].x, h11 = hl1[i2].y;
        #pragma unroll
        for (int q = 0; q < 4; ++q) {
            const float4 wa = w0[q];
            const float4 wb = w1[q];
            const v2f wlo = {wa.x, wa.y}, whi = {wa.z, wa.w};
            const v2f vlo = {wb.x, wb.y}, vhi = {wb.z, wb.w};
            a0[2 * q]     += h00 * wlo + h01 * vlo;
            a0[2 * q + 1] += h00 * whi + h01 * vhi;
            a1[2 * q]     += h10 * wlo + h11 * vlo;
            a1[2 * q + 1] += h10 * whi + h11 * vhi;
        }
    }
    v2f b0[8], b1[8];
    #pragma unroll
    for (int j = 0; j < 8; ++j) {
        b0[j] = __builtin_elementwise_max(a0[j], zz);
        b1[j] = __builtin_elementwise_max(a1[j], zz);
    }

    #pragma unroll
    for (int j = 0; j < 8; ++j) { a0[j] = zz; a1[j] = zz; }
    #pragma unroll
    for (int i2 = 0; i2 < 8; ++i2) {
        const float4* w0 = reinterpret_cast<const float4*>(&sW1t[(2 * i2) * 16]);
        const float4* w1 = reinterpret_cast<const float4*>(&sW1t[(2 * i2 + 1) * 16]);
        const float h00 = b0[i2].x, h01 = b0[i2].y;
        const float h10 = b1[i2].x, h11 = b1[i2].y;
        #pragma unroll
        for (int q = 0; q < 4; ++q) {
            const float4 wa = w0[q];
            const float4 wb = w1[q];
            const v2f wlo = {wa.x, wa.y}, whi = {wa.z, wa.w};
            const v2f vlo = {wb.x, wb.y}, vhi = {wb.z, wb.w};
            a0[2 * q]     += h00 * wlo + h01 * vlo;
            a0[2 * q + 1] += h00 * whi + h01 * vhi;
            a1[2 * q]     += h10 * wlo + h11 * vlo;
            a1[2 * q + 1] += h10 * whi + h11 * vhi;
        }
    }

    v2f acc0 = zz, acc1 = zz;
    #pragma unroll
    for (int j = 0; j < 8; ++j) {
        const v2f w2 = {sW2[2 * j], sW2[2 * j + 1]};
        acc0 += __builtin_elementwise_max(a0[j], zz) * w2;
        acc1 += __builtin_elementwise_max(a1[j], zz) * w2;
    }
    __builtin_nontemporal_store(acc0.x + acc0.y, out + p0);
    if (g + Nh < N)
        __builtin_nontemporal_store(acc1.x + acc1.y, out + g + Nh);
}

// ---- fallback: direct f32 row-major gather, if ws too small ----
__global__ __launch_bounds__(256) void sdf_fused_fallback(
    const float* __restrict__ x,
    const float* __restrict__ table,
    const float* __restrict__ W0,
    const float* __restrict__ W1,
    const float* __restrict__ W2,
    float* __restrict__ out,
    int N, EncParams ep)
{
    __shared__ __align__(16) float sW0t[256];
    __shared__ __align__(16) float sW1t[256];
    __shared__ __align__(16) float sW2[16];

    const int t = threadIdx.x;
    sW0t[(t & 15) * 16 + (t >> 4)] = W0[t];
    sW1t[(t & 15) * 16 + (t >> 4)] = W1[t];
    if (t < 16) sW2[t] = W2[t];
    __syncthreads();

    const int gid = blockIdx.x * 256 + t;
    if (gid >= N) return;

    const float px = x[3 * gid + 0];
    const float py = x[3 * gid + 1];
    const float pz = x[3 * gid + 2];

    v2f hl[8];
    #pragma unroll
    for (int l = 0; l < 8; ++l) {
        const int side  = SIDE[l];
        const int side2 = side * side;
        const float s = ep.scale[l];
        const float fx = px * s + 0.5f;
        const float fy = py * s + 0.5f;
        const float fz = pz * s + 0.5f;
        const float gx = floorf(fx), gy = floorf(fy), gz = floorf(fz);
        const float rx = fx - gx, ry = fy - gy, rz = fz - gz;
        const int ix = (int)gx, iy = (int)gy, iz = (int)gz;
        const int base = ROWOFF[l] + ix + iy * side + iz * side2;
        const float wx0 = 1.0f - rx, wy0 = 1.0f - ry, wz0 = 1.0f - rz;

        v2f acc = {0.0f, 0.0f};
        #pragma unroll
        for (int dz = 0; dz < 2; ++dz) {
            const float wz = dz ? rz : wz0;
            #pragma unroll
            for (int dy = 0; dy < 2; ++dy) {
                const float wyz = (dy ? ry : wy0) * wz;
                const int r = base + dy * side + dz * side2;
                const float4 f = *reinterpret_cast<const float4*>(table + 2 * r);
                acc += (wyz * wx0) * (v2f){f.x, f.y}
                     + (wyz * rx)  * (v2f){f.z, f.w};
            }
        }
        hl[l] = acc;
    }

    v2f a[8];
    #pragma unroll
    for (int j = 0; j < 8; ++j) a[j] = (v2f){0.0f, 0.0f};
    #pragma unroll
    for (int i2 = 0; i2 < 8; ++i2) {
        const float h0 = hl[i2].x;
        const float h1 = hl[i2].y;
        const float4* w0 = reinterpret_cast<const float4*>(&sW0t[(2 * i2) * 16]);
        const float4* w1 = reinterpret_cast<const float4*>(&sW0t[(2 * i2 + 1) * 16]);
        #pragma unroll
        for (int q = 0; q < 4; ++q) {
            const float4 wa = w0[q];
            const float4 wb = w1[q];
            a[2 * q]     += h0 * (v2f){wa.x, wa.y} + h1 * (v2f){wb.x, wb.y};
            a[2 * q + 1] += h0 * (v2f){wa.z, wa.w} + h1 * (v2f){wb.z, wb.w};
        }
    }
    const v2f zz = {0.0f, 0.0f};
    v2f h1v[8];
    #pragma unroll
    for (int j = 0; j < 8; ++j) h1v[j] = __builtin_elementwise_max(a[j], zz);

    #pragma unroll
    for (int j = 0; j < 8; ++j) a[j] = (v2f){0.0f, 0.0f};
    #pragma unroll
    for (int i2 = 0; i2 < 8; ++i2) {
        const float h0 = h1v[i2].x;
        const float h1 = h1v[i2].y;
        const float4* w0 = reinterpret_cast<const float4*>(&sW1t[(2 * i2) * 16]);
        const float4* w1 = reinterpret_cast<const float4*>(&sW1t[(2 * i2 + 1) * 16]);
        #pragma unroll
        for (int q = 0; q < 4; ++q) {
            const float4 wa = w0[q];
            const float4 wb = w1[q];
            a[2 * q]     += h0 * (v2f){wa.x, wa.y} + h1 * (v2f){wb.x, wb.y};
            a[2 * q + 1] += h0 * (v2f){wa.z, wa.w} + h1 * (v2f){wb.z, wb.w};
        }
    }

    v2f acco = {0.0f, 0.0f};
    #pragma unroll
    for (int j = 0; j < 8; ++j) {
        const v2f h2 = __builtin_elementwise_max(a[j], zz);
        acco += h2 * (v2f){sW2[2 * j], sW2[2 * j + 1]};
    }
    out[gid] = acco.x + acco.y;
}

extern "C" void kernel_launch(void* const* d_in, const int* in_sizes, int n_in,
                              void* d_out, int out_size, void* d_ws, size_t ws_size,
                              hipStream_t stream) {
    const float* x     = (const float*)d_in[0];
    const float* table = (const float*)d_in[1];
    const float* W0    = (const float*)d_in[2];
    const float* W1    = (const float*)d_in[3];
    const float* W2    = (const float*)d_in[4];
    float* out = (float*)d_out;

    const int N = in_sizes[0] / 3;

    EncParams ep;
    const double g = pow(4.0, 1.0 / 7.0);
    for (int l = 0; l < 8; ++l) {
        ep.scale[l] = (float)(8.0 * pow(g, (double)l) - 1.0);
    }

    const size_t needBytes = (size_t)TOTCELLS * 32;

    if (ws_size >= needBytes) {
        uint4* cellsH = (uint4*)d_ws;
        hipLaunchKernelGGL(build_cells_h, dim3((TOTCELLS + 255) / 256), dim3(256),
                           0, stream, table, cellsH);
        const int Nh = (N + 1) / 2;
        const int blocks = (Nh + 255) / 256;
        hipLaunchKernelGGL(sdf_main, dim3(blocks), dim3(256), 0, stream,
                           x, cellsH, W0, W1, W2, out, N, Nh, ep);
    } else {
        const int blocks = (N + 255) / 256;
        hipLaunchKernelGGL(sdf_fused_fallback, dim3(blocks), dim3(256), 0, stream,
                           x, table, W0, W1, W2, out, N, ep);
    }
}

// Round 7
// 193.023 us; speedup vs baseline: 7.0349x; 7.0349x over previous
//
#include <hip/hip_runtime.h>
#include <math.h>

// Round 7: revert the round-6 spill, keep its good ideas.
// Round 6 post-mortem: 2 pts/thread needed ~200 VGPR but launch_bounds(256,3)
// capped at 84 -> scratch spills -> 5.5GB HBM traffic/dispatch, 1456us.
// This round: round-5 structure (1 pt/thread) + all-8-levels fp16 cells
// (no LDS rows -> no 9.4M conflict cycles, no 17-load fill) + packed-fp16
// nested-lerp interp (v_pk_fma_f16, no per-corner cvt) + launch_bounds(256,2).

typedef float  v2f __attribute__((ext_vector_type(2)));
typedef _Float16 h2 __attribute__((ext_vector_type(2)));

struct EncParams { float scale[8]; };

__constant__ constexpr int SIDE[8]   = {9, 11, 13, 16, 19, 23, 28, 33};
__constant__ constexpr int ROWOFF[8] = {0, 729, 2060, 4257, 8353, 15212, 27379, 49331};
__constant__ constexpr int CS[8]     = {8, 10, 12, 15, 18, 22, 27, 32};
__constant__ constexpr int CB[8]     = {0, 512, 1512, 3240, 6615, 12447, 23095, 42778};
#define TOTCELLS 75546   // sum of (side-1)^3 over all 8 levels

__device__ __forceinline__ unsigned int pack2h(float a, float b) {
    _Float16 ha = (_Float16)a, hb = (_Float16)b;
    unsigned short ua = __builtin_bit_cast(unsigned short, ha);
    unsigned short ub = __builtin_bit_cast(unsigned short, hb);
    return (unsigned int)ua | ((unsigned int)ub << 16);
}
__device__ __forceinline__ h2 as_h2(unsigned int u) {
    return __builtin_bit_cast(h2, u);
}

// ---- build fp16 per-cell 32B corner blocks, ALL levels ----
// cell c: 2x uint4. qa={q0.lo,q0.hi,q1.lo,q1.hi}, qb={q2.lo,q2.hi,q3.lo,q3.hi}
// q = dz*2+dy; lo = half2 feats at x-corner 0, hi = at x-corner 1.
__global__ __launch_bounds__(256) void build_cells_h(
    const float* __restrict__ table, uint4* __restrict__ cellsH)
{
    const int c = blockIdx.x * 256 + threadIdx.x;
    if (c >= TOTCELLS) return;

    int l = 0;
    #pragma unroll
    for (int i = 1; i < 8; ++i) if (c >= CB[i]) l = i;

    const int cs  = CS[l];
    const int rem = c - CB[l];
    const int ix  = rem % cs;
    const int t1  = rem / cs;
    const int iy  = t1 % cs;
    const int iz  = t1 / cs;

    const int side  = SIDE[l];
    const int side2 = side * side;
    const int row   = ROWOFF[l] + ix + iy * side + iz * side2;

    unsigned int q[8];
    #pragma unroll
    for (int dz = 0; dz < 2; ++dz) {
        #pragma unroll
        for (int dy = 0; dy < 2; ++dy) {
            const int r = row + dy * side + dz * side2;
            q[(dz * 2 + dy) * 2 + 0] = pack2h(table[2 * r + 0], table[2 * r + 1]);
            q[(dz * 2 + dy) * 2 + 1] = pack2h(table[2 * r + 2], table[2 * r + 3]);
        }
    }
    cellsH[2 * c + 0] = make_uint4(q[0], q[1], q[2], q[3]);
    cellsH[2 * c + 1] = make_uint4(q[4], q[5], q[6], q[7]);
}

__device__ __forceinline__ h2 lerp_h2(h2 a, h2 b, h2 r) {
    return a + r * (b - a);   // v_pk_add/sub/fma_f16
}

// ---- main fused kernel: 1 point per thread ----
__global__ __launch_bounds__(256, 2) void sdf_main(
    const float* __restrict__ x,
    const uint4* __restrict__ cellsH,
    const float* __restrict__ W0,
    const float* __restrict__ W1,
    const float* __restrict__ W2,
    float* __restrict__ out,
    int N, EncParams ep)
{
    __shared__ __align__(16) float sW0t[256];    // transposed [i][j]
    __shared__ __align__(16) float sW1t[256];
    __shared__ __align__(16) float sW2[16];

    const int t = threadIdx.x;
    sW0t[(t & 15) * 16 + (t >> 4)] = W0[t];
    sW1t[(t & 15) * 16 + (t >> 4)] = W1[t];
    if (t < 16) sW2[t] = W2[t];
    __syncthreads();

    const int gid = blockIdx.x * 256 + t;
    if (gid >= N) return;

    const float px = __builtin_nontemporal_load(x + 3 * gid + 0);
    const float py = __builtin_nontemporal_load(x + 3 * gid + 1);
    const float pz = __builtin_nontemporal_load(x + 3 * gid + 2);

    // ---- phase A: fracs (packed fp16) + cell indices for all 8 levels ----
    h2 rrx[8], rry[8], rrz[8];
    int cidx[8];
    #pragma unroll
    for (int l = 0; l < 8; ++l) {
        const float s = ep.scale[l];
        const float fx = px * s + 0.5f;
        const float fy = py * s + 0.5f;
        const float fz = pz * s + 0.5f;
        const float gx = floorf(fx), gy = floorf(fy), gz = floorf(fz);
        const _Float16 hx = (_Float16)(fx - gx);
        const _Float16 hy = (_Float16)(fy - gy);
        const _Float16 hz = (_Float16)(fz - gz);
        rrx[l] = (h2){hx, hx};
        rry[l] = (h2){hy, hy};
        rrz[l] = (h2){hz, hz};
        cidx[l] = CB[l] + (((int)gz * CS[l] + (int)gy) * CS[l] + (int)gx);
    }

    // ---- phase B: issue all 16 cell loads (ILP) ----
    uint4 qa[8], qb[8];
    #pragma unroll
    for (int l = 0; l < 8; ++l) {
        const uint4* cp = cellsH + 2 * cidx[l];
        qa[l] = cp[0];
        qb[l] = cp[1];
    }

    // ---- phase C: packed-fp16 nested lerp, then cvt to f32 features ----
    v2f hl[8];
    #pragma unroll
    for (int l = 0; l < 8; ++l) {
        const h2 v00 = lerp_h2(as_h2(qa[l].x), as_h2(qa[l].y), rrx[l]);
        const h2 v01 = lerp_h2(as_h2(qa[l].z), as_h2(qa[l].w), rrx[l]);
        const h2 v10 = lerp_h2(as_h2(qb[l].x), as_h2(qb[l].y), rrx[l]);
        const h2 v11 = lerp_h2(as_h2(qb[l].z), as_h2(qb[l].w), rrx[l]);
        const h2 v0  = lerp_h2(v00, v01, rry[l]);
        const h2 v1  = lerp_h2(v10, v11, rry[l]);
        const h2 hv  = lerp_h2(v0, v1, rrz[l]);
        hl[l] = (v2f){(float)hv.x, (float)hv.y};
    }

    // ---- MLP, packed fp32 ----
    const v2f zz = {0.0f, 0.0f};
    v2f a[8];
    #pragma unroll
    for (int j = 0; j < 8; ++j) a[j] = zz;
    #pragma unroll
    for (int i2 = 0; i2 < 8; ++i2) {
        const float h0 = hl[i2].x;
        const float h1 = hl[i2].y;
        const float4* w0 = reinterpret_cast<const float4*>(&sW0t[(2 * i2) * 16]);
        const float4* w1 = reinterpret_cast<const float4*>(&sW0t[(2 * i2 + 1) * 16]);
        #pragma unroll
        for (int q = 0; q < 4; ++q) {
            const float4 wa = w0[q];
            const float4 wb = w1[q];
            a[2 * q]     += h0 * (v2f){wa.x, wa.y} + h1 * (v2f){wb.x, wb.y};
            a[2 * q + 1] += h0 * (v2f){wa.z, wa.w} + h1 * (v2f){wb.z, wb.w};
        }
    }
    v2f h1v[8];
    #pragma unroll
    for (int j = 0; j < 8; ++j) h1v[j] = __builtin_elementwise_max(a[j], zz);

    #pragma unroll
    for (int j = 0; j < 8; ++j) a[j] = zz;
    #pragma unroll
    for (int i2 = 0; i2 < 8; ++i2) {
        const float h0 = h1v[i2].x;
        const float h1 = h1v[i2].y;
        const float4* w0 = reinterpret_cast<const float4*>(&sW1t[(2 * i2) * 16]);
        const float4* w1 = reinterpret_cast<const float4*>(&sW1t[(2 * i2 + 1) * 16]);
        #pragma unroll
        for (int q = 0; q < 4; ++q) {
            const float4 wa = w0[q];
            const float4 wb = w1[q];
            a[2 * q]     += h0 * (v2f){wa.x, wa.y} + h1 * (v2f){wb.x, wb.y};
            a[2 * q + 1] += h0 * (v2f){wa.z, wa.w} + h1 * (v2f){wb.z, wb.w};
        }
    }

    v2f acco = zz;
    #pragma unroll
    for (int j = 0; j < 8; ++j) {
        const v2f hh = __builtin_elementwise_max(a[j], zz);
        acco += hh * (v2f){sW2[2 * j], sW2[2 * j + 1]};
    }
    __builtin_nontemporal_store(acco.x + acco.y, out + gid);
}

// ---- fallback: direct f32 row-major gather, if ws too small ----
__global__ __launch_bounds__(256) void sdf_fused_fallback(
    const float* __restrict__ x,
    const float* __restrict__ table,
    const float* __restrict__ W0,
    const float* __restrict__ W1,
    const float* __restrict__ W2,
    float* __restrict__ out,
    int N, EncParams ep)
{
    __shared__ __align__(16) float sW0t[256];
    __shared__ __align__(16) float sW1t[256];
    __shared__ __align__(16) float sW2[16];

    const int t = threadIdx.x;
    sW0t[(t & 15) * 16 + (t >> 4)] = W0[t];
    sW1t[(t & 15) * 16 + (t >> 4)] = W1[t];
    if (t < 16) sW2[t] = W2[t];
    __syncthreads();

    const int gid = blockIdx.x * 256 + t;
    if (gid >= N) return;

    const float px = x[3 * gid + 0];
    const float py = x[3 * gid + 1];
    const float pz = x[3 * gid + 2];

    v2f hl[8];
    #pragma unroll
    for (int l = 0; l < 8; ++l) {
        const int side  = SIDE[l];
        const int side2 = side * side;
        const float s = ep.scale[l];
        const float fx = px * s + 0.5f;
        const float fy = py * s + 0.5f;
        const float fz = pz * s + 0.5f;
        const float gx = floorf(fx), gy = floorf(fy), gz = floorf(fz);
        const float rx = fx - gx, ry = fy - gy, rz = fz - gz;
        const int ix = (int)gx, iy = (int)gy, iz = (int)gz;
        const int base = ROWOFF[l] + ix + iy * side + iz * side2;
        const float wx0 = 1.0f - rx, wy0 = 1.0f - ry, wz0 = 1.0f - rz;

        v2f acc = {0.0f, 0.0f};
        #pragma unroll
        for (int dz = 0; dz < 2; ++dz) {
            const float wz = dz ? rz : wz0;
            #pragma unroll
            for (int dy = 0; dy < 2; ++dy) {
                const float wyz = (dy ? ry : wy0) * wz;
                const int r = base + dy * side + dz * side2;
                const float4 f = *reinterpret_cast<const float4*>(table + 2 * r);
                acc += (wyz * wx0) * (v2f){f.x, f.y}
                     + (wyz * rx)  * (v2f){f.z, f.w};
            }
        }
        hl[l] = acc;
    }

    v2f a[8];
    #pragma unroll
    for (int j = 0; j < 8; ++j) a[j] = (v2f){0.0f, 0.0f};
    #pragma unroll
    for (int i2 = 0; i2 < 8; ++i2) {
        const float h0 = hl[i2].x;
        const float h1 = hl[i2].y;
        const float4* w0 = reinterpret_cast<const float4*>(&sW0t[(2 * i2) * 16]);
        const float4* w1 = reinterpret_cast<const float4*>(&sW0t[(2 * i2 + 1) * 16]);
        #pragma unroll
        for (int q = 0; q < 4; ++q) {
            const float4 wa = w0[q];
            const float4 wb = w1[q];
            a[2 * q]     += h0 * (v2f){wa.x, wa.y} + h1 * (v2f){wb.x, wb.y};
            a[2 * q + 1] += h0 * (v2f){wa.z, wa.w} + h1 * (v2f){wb.z, wb.w};
        }
    }
    const v2f zz = {0.0f, 0.0f};
    v2f h1v[8];
    #pragma unroll
    for (int j = 0; j < 8; ++j) h1v[j] = __builtin_elementwise_max(a[j], zz);

    #pragma unroll
    for (int j = 0; j < 8; ++j) a[j] = (v2f){0.0f, 0.0f};
    #pragma unroll
    for (int i2 = 0; i2 < 8; ++i2) {
        const float h0 = h1v[i2].x;
        const float h1 = h1v[i2].y;
        const float4* w0 = reinterpret_cast<const float4*>(&sW1t[(2 * i2) * 16]);
        const float4* w1 = reinterpret_cast<const float4*>(&sW1t[(2 * i2 + 1) * 16]);
        #pragma unroll
        for (int q = 0; q < 4; ++q) {
            const float4 wa = w0[q];
            const float4 wb = w1[q];
            a[2 * q]     += h0 * (v2f){wa.x, wa.y} + h1 * (v2f){wb.x, wb.y};
            a[2 * q + 1] += h0 * (v2f){wa.z, wa.w} + h1 * (v2f){wb.z, wb.w};
        }
    }

    v2f acco = {0.0f, 0.0f};
    #pragma unroll
    for (int j = 0; j < 8; ++j) {
        const v2f h2v = __builtin_elementwise_max(a[j], zz);
        acco += h2v * (v2f){sW2[2 * j], sW2[2 * j + 1]};
    }
    out[gid] = acco.x + acco.y;
}

extern "C" void kernel_launch(void* const* d_in, const int* in_sizes, int n_in,
                              void* d_out, int out_size, void* d_ws, size_t ws_size,
                              hipStream_t stream) {
    const float* x     = (const float*)d_in[0];
    const float* table = (const float*)d_in[1];
    const float* W0    = (const float*)d_in[2];
    const float* W1    = (const float*)d_in[3];
    const float* W2    = (const float*)d_in[4];
    float* out = (float*)d_out;

    const int N = in_sizes[0] / 3;

    EncParams ep;
    const double g = pow(4.0, 1.0 / 7.0);
    for (int l = 0; l < 8; ++l) {
        ep.scale[l] = (float)(8.0 * pow(g, (double)l) - 1.0);
    }

    const size_t needBytes = (size_t)TOTCELLS * 32;
    const int blocks = (N + 255) / 256;

    if (ws_size >= needBytes) {
        uint4* cellsH = (uint4*)d_ws;
        hipLaunchKernelGGL(build_cells_h, dim3((TOTCELLS + 255) / 256), dim3(256),
                           0, stream, table, cellsH);
        hipLaunchKernelGGL(sdf_main, dim3(blocks), dim3(256), 0, stream,
                           x, cellsH, W0, W1, W2, out, N, ep);
    } else {
        hipLaunchKernelGGL(sdf_fused_fallback, dim3(blocks), dim3(256), 0, stream,
                           x, table, W0, W1, W2, out, N, ep);
    }
}

// Round 8
// 145.063 us; speedup vs baseline: 9.3608x; 1.3306x over previous
//
#include <hip/hip_runtime.h>
#include <math.h>

// Round 8: best-of-5-and-7.
// R5 (166us): LDS coarse levels + f32 lerp, VALU-bound (61%).
// R7 (213us): all-global fp16 cells + pk-fp16 lerp, transaction-bound (39%).
// Lesson: divergent global gather ~10-12us/level, divergent LDS read ~5us/level,
// pk-fp16 lerp saves ~30us of VALU. So: levels 0-3 from LDS fp16 rows
// (rows 0..8353 = 33.4KB, contiguous by layout), levels 4-7 from fp16 cells
// (one 64B line per point-level), pk-fp16 nested lerp on BOTH paths.
// Global gathers 16 -> 8 per thread. launch_bounds(256,2): no spill risk.

typedef float    v2f __attribute__((ext_vector_type(2)));
typedef _Float16 h2  __attribute__((ext_vector_type(2)));

struct EncParams { float scale[8]; };

__constant__ constexpr int SIDE[8]   = {9, 11, 13, 16, 19, 23, 28, 33};
__constant__ constexpr int ROWOFF[8] = {0, 729, 2060, 4257, 8353, 15212, 27379, 49331};
__constant__ constexpr int CS[8]     = {8, 10, 12, 15, 18, 22, 27, 32};
// fine-level cell bases, rebased to 0 at level 4
__constant__ constexpr int CBF[8]    = {0, 0, 0, 0, 0, 5832, 16480, 36163};
#define NROWS_L  8353    // rows of levels 0..3 (= ROWOFF[4])
#define NCELLS_F 68931   // cells of levels 4..7

__device__ __forceinline__ unsigned int pack2h(float a, float b) {
    _Float16 ha = (_Float16)a, hb = (_Float16)b;
    unsigned short ua = __builtin_bit_cast(unsigned short, ha);
    unsigned short ub = __builtin_bit_cast(unsigned short, hb);
    return (unsigned int)ua | ((unsigned int)ub << 16);
}
__device__ __forceinline__ h2 as_h2(unsigned int u) {
    return __builtin_bit_cast(h2, u);
}
__device__ __forceinline__ h2 lerp_h2(h2 a, h2 b, h2 r) {
    return a + r * (b - a);   // v_pk_sub/fma_f16
}

// ---- build fp16 row copy of levels 0..3 ----
__global__ __launch_bounds__(256) void build_rows_h(
    const float* __restrict__ table, unsigned int* __restrict__ rowsH)
{
    const int i = blockIdx.x * 256 + threadIdx.x;
    if (i >= NROWS_L) return;
    rowsH[i] = pack2h(table[2 * i], table[2 * i + 1]);
}

// ---- build fp16 per-cell 32B corner blocks for levels 4..7 ----
// cell c: 2x uint4. qa={q0.lo,q0.hi,q1.lo,q1.hi}, qb={q2.lo,q2.hi,q3.lo,q3.hi}
// q = dz*2+dy; lo = half2 feats at x-corner 0, hi = at x-corner 1.
__global__ __launch_bounds__(256) void build_cells_f(
    const float* __restrict__ table, uint4* __restrict__ cellsF)
{
    const int c = blockIdx.x * 256 + threadIdx.x;
    if (c >= NCELLS_F) return;

    int l = 4;
    #pragma unroll
    for (int i = 5; i < 8; ++i) if (c >= CBF[i]) l = i;

    const int cs  = CS[l];
    const int rem = c - CBF[l];
    const int ix  = rem % cs;
    const int t1  = rem / cs;
    const int iy  = t1 % cs;
    const int iz  = t1 / cs;

    const int side  = SIDE[l];
    const int side2 = side * side;
    const int row   = ROWOFF[l] + ix + iy * side + iz * side2;

    unsigned int q[8];
    #pragma unroll
    for (int dz = 0; dz < 2; ++dz) {
        #pragma unroll
        for (int dy = 0; dy < 2; ++dy) {
            const int r = row + dy * side + dz * side2;
            q[(dz * 2 + dy) * 2 + 0] = pack2h(table[2 * r + 0], table[2 * r + 1]);
            q[(dz * 2 + dy) * 2 + 1] = pack2h(table[2 * r + 2], table[2 * r + 3]);
        }
    }
    cellsF[2 * c + 0] = make_uint4(q[0], q[1], q[2], q[3]);
    cellsF[2 * c + 1] = make_uint4(q[4], q[5], q[6], q[7]);
}

// ---- main fused kernel ----
__global__ __launch_bounds__(256, 2) void sdf_main(
    const float* __restrict__ x,
    const unsigned int* __restrict__ rowsH,
    const uint4* __restrict__ cellsF,
    const float* __restrict__ W0,
    const float* __restrict__ W1,
    const float* __restrict__ W2,
    float* __restrict__ out,
    int N, EncParams ep)
{
    __shared__ __align__(16) unsigned int sRows[NROWS_L];   // 33,412 B
    __shared__ __align__(16) float sW0t[256];               // transposed [i][j]
    __shared__ __align__(16) float sW1t[256];
    __shared__ __align__(16) float sW2[16];

    const int t = threadIdx.x;
    sW0t[(t & 15) * 16 + (t >> 4)] = W0[t];
    sW1t[(t & 15) * 16 + (t >> 4)] = W1[t];
    if (t < 16) sW2[t] = W2[t];
    {
        // 8353 = 2088*4 + 1; coalesced uint4 fill
        uint4* s4 = reinterpret_cast<uint4*>(sRows);
        const uint4* g4 = reinterpret_cast<const uint4*>(rowsH);
        for (int i = t; i < NROWS_L / 4; i += 256) s4[i] = g4[i];
        if (t == 0) sRows[NROWS_L - 1] = rowsH[NROWS_L - 1];
    }
    __syncthreads();

    const int gid = blockIdx.x * 256 + t;
    if (gid >= N) return;

    const float px = __builtin_nontemporal_load(x + 3 * gid + 0);
    const float py = __builtin_nontemporal_load(x + 3 * gid + 1);
    const float pz = __builtin_nontemporal_load(x + 3 * gid + 2);

    // ---- phase A: fp16 fracs + indices for all 8 levels ----
    h2 rrx[8], rry[8], rrz[8];
    int rbase[4];   // levels 0..3: row index into sRows
    int cidx[4];    // levels 4..7: cell index into cellsF
    #pragma unroll
    for (int l = 0; l < 8; ++l) {
        const float s = ep.scale[l];
        const float fx = px * s + 0.5f;
        const float fy = py * s + 0.5f;
        const float fz = pz * s + 0.5f;
        const float gx = floorf(fx), gy = floorf(fy), gz = floorf(fz);
        const _Float16 hx = (_Float16)(fx - gx);
        const _Float16 hy = (_Float16)(fy - gy);
        const _Float16 hz = (_Float16)(fz - gz);
        rrx[l] = (h2){hx, hx};
        rry[l] = (h2){hy, hy};
        rrz[l] = (h2){hz, hz};
        const int ix = (int)gx, iy = (int)gy, iz = (int)gz;
        if (l < 4) {
            rbase[l] = ROWOFF[l] + ix + iy * SIDE[l] + iz * SIDE[l] * SIDE[l];
        } else {
            cidx[l - 4] = CBF[l] + ((iz * CS[l] + iy) * CS[l] + ix);
        }
    }

    // ---- phase B: issue all 8 fine-level loads (ILP) ----
    uint4 qa[4], qb[4];
    #pragma unroll
    for (int k = 0; k < 4; ++k) {
        const uint4* cp = cellsF + 2 * cidx[k];
        qa[k] = cp[0];
        qb[k] = cp[1];
    }

    v2f hl[8];

    // ---- phase C1: levels 0..3 from LDS (overlaps global loads) ----
    #pragma unroll
    for (int l = 0; l < 4; ++l) {
        const int side = SIDE[l], side2 = side * side;
        const int r00 = rbase[l];
        const int r01 = r00 + side;
        const int r10 = r00 + side2;
        const int r11 = r10 + side;
        const unsigned int a00 = sRows[r00], a01 = sRows[r00 + 1];
        const unsigned int b00 = sRows[r01], b01 = sRows[r01 + 1];
        const unsigned int c00 = sRows[r10], c01 = sRows[r10 + 1];
        const unsigned int d00 = sRows[r11], d01 = sRows[r11 + 1];
        const h2 v00 = lerp_h2(as_h2(a00), as_h2(a01), rrx[l]);
        const h2 v01 = lerp_h2(as_h2(b00), as_h2(b01), rrx[l]);
        const h2 v10 = lerp_h2(as_h2(c00), as_h2(c01), rrx[l]);
        const h2 v11 = lerp_h2(as_h2(d00), as_h2(d01), rrx[l]);
        const h2 v0  = lerp_h2(v00, v01, rry[l]);
        const h2 v1  = lerp_h2(v10, v11, rry[l]);
        const h2 hv  = lerp_h2(v0, v1, rrz[l]);
        hl[l] = (v2f){(float)hv.x, (float)hv.y};
    }

    // ---- phase C2: levels 4..7 from the fp16 cell array ----
    #pragma unroll
    for (int k = 0; k < 4; ++k) {
        const int l = k + 4;
        const h2 v00 = lerp_h2(as_h2(qa[k].x), as_h2(qa[k].y), rrx[l]);
        const h2 v01 = lerp_h2(as_h2(qa[k].z), as_h2(qa[k].w), rrx[l]);
        const h2 v10 = lerp_h2(as_h2(qb[k].x), as_h2(qb[k].y), rrx[l]);
        const h2 v11 = lerp_h2(as_h2(qb[k].z), as_h2(qb[k].w), rrx[l]);
        const h2 v0  = lerp_h2(v00, v01, rry[l]);
        const h2 v1  = lerp_h2(v10, v11, rry[l]);
        const h2 hv  = lerp_h2(v0, v1, rrz[l]);
        hl[l] = (v2f){(float)hv.x, (float)hv.y};
    }

    // ---- MLP, packed fp32 ----
    const v2f zz = {0.0f, 0.0f};
    v2f a[8];
    #pragma unroll
    for (int j = 0; j < 8; ++j) a[j] = zz;
    #pragma unroll
    for (int i2 = 0; i2 < 8; ++i2) {
        const float h0 = hl[i2].x;
        const float h1 = hl[i2].y;
        const float4* w0 = reinterpret_cast<const float4*>(&sW0t[(2 * i2) * 16]);
        const float4* w1 = reinterpret_cast<const float4*>(&sW0t[(2 * i2 + 1) * 16]);
        #pragma unroll
        for (int q = 0; q < 4; ++q) {
            const float4 wa = w0[q];
            const float4 wb = w1[q];
            a[2 * q]     += h0 * (v2f){wa.x, wa.y} + h1 * (v2f){wb.x, wb.y};
            a[2 * q + 1] += h0 * (v2f){wa.z, wa.w} + h1 * (v2f){wb.z, wb.w};
        }
    }
    v2f h1v[8];
    #pragma unroll
    for (int j = 0; j < 8; ++j) h1v[j] = __builtin_elementwise_max(a[j], zz);

    #pragma unroll
    for (int j = 0; j < 8; ++j) a[j] = zz;
    #pragma unroll
    for (int i2 = 0; i2 < 8; ++i2) {
        const float h0 = h1v[i2].x;
        const float h1 = h1v[i2].y;
        const float4* w0 = reinterpret_cast<const float4*>(&sW1t[(2 * i2) * 16]);
        const float4* w1 = reinterpret_cast<const float4*>(&sW1t[(2 * i2 + 1) * 16]);
        #pragma unroll
        for (int q = 0; q < 4; ++q) {
            const float4 wa = w0[q];
            const float4 wb = w1[q];
            a[2 * q]     += h0 * (v2f){wa.x, wa.y} + h1 * (v2f){wb.x, wb.y};
            a[2 * q + 1] += h0 * (v2f){wa.z, wa.w} + h1 * (v2f){wb.z, wb.w};
        }
    }

    v2f acco = zz;
    #pragma unroll
    for (int j = 0; j < 8; ++j) {
        const v2f hh = __builtin_elementwise_max(a[j], zz);
        acco += hh * (v2f){sW2[2 * j], sW2[2 * j + 1]};
    }
    __builtin_nontemporal_store(acco.x + acco.y, out + gid);
}

// ---- fallback: direct f32 row-major gather, if ws too small ----
__global__ __launch_bounds__(256) void sdf_fused_fallback(
    const float* __restrict__ x,
    const float* __restrict__ table,
    const float* __restrict__ W0,
    const float* __restrict__ W1,
    const float* __restrict__ W2,
    float* __restrict__ out,
    int N, EncParams ep)
{
    __shared__ __align__(16) float sW0t[256];
    __shared__ __align__(16) float sW1t[256];
    __shared__ __align__(16) float sW2[16];

    const int t = threadIdx.x;
    sW0t[(t & 15) * 16 + (t >> 4)] = W0[t];
    sW1t[(t & 15) * 16 + (t >> 4)] = W1[t];
    if (t < 16) sW2[t] = W2[t];
    __syncthreads();

    const int gid = blockIdx.x * 256 + t;
    if (gid >= N) return;

    const float px = x[3 * gid + 0];
    const float py = x[3 * gid + 1];
    const float pz = x[3 * gid + 2];

    v2f hl[8];
    #pragma unroll
    for (int l = 0; l < 8; ++l) {
        const int side  = SIDE[l];
        const int side2 = side * side;
        const float s = ep.scale[l];
        const float fx = px * s + 0.5f;
        const float fy = py * s + 0.5f;
        const float fz = pz * s + 0.5f;
        const float gx = floorf(fx), gy = floorf(fy), gz = floorf(fz);
        const float rx = fx - gx, ry = fy - gy, rz = fz - gz;
        const int ix = (int)gx, iy = (int)gy, iz = (int)gz;
        const int base = ROWOFF[l] + ix + iy * side + iz * side2;
        const float wx0 = 1.0f - rx, wy0 = 1.0f - ry, wz0 = 1.0f - rz;

        v2f acc = {0.0f, 0.0f};
        #pragma unroll
        for (int dz = 0; dz < 2; ++dz) {
            const float wz = dz ? rz : wz0;
            #pragma unroll
            for (int dy = 0; dy < 2; ++dy) {
                const float wyz = (dy ? ry : wy0) * wz;
                const int r = base + dy * side + dz * side2;
                const float4 f = *reinterpret_cast<const float4*>(table + 2 * r);
                acc += (wyz * wx0) * (v2f){f.x, f.y}
                     + (wyz * rx)  * (v2f){f.z, f.w};
            }
        }
        hl[l] = acc;
    }

    v2f a[8];
    #pragma unroll
    for (int j = 0; j < 8; ++j) a[j] = (v2f){0.0f, 0.0f};
    #pragma unroll
    for (int i2 = 0; i2 < 8; ++i2) {
        const float h0 = hl[i2].x;
        const float h1 = hl[i2].y;
        const float4* w0 = reinterpret_cast<const float4*>(&sW0t[(2 * i2) * 16]);
        const float4* w1 = reinterpret_cast<const float4*>(&sW0t[(2 * i2 + 1) * 16]);
        #pragma unroll
        for (int q = 0; q < 4; ++q) {
            const float4 wa = w0[q];
            const float4 wb = w1[q];
            a[2 * q]     += h0 * (v2f){wa.x, wa.y} + h1 * (v2f){wb.x, wb.y};
            a[2 * q + 1] += h0 * (v2f){wa.z, wa.w} + h1 * (v2f){wb.z, wb.w};
        }
    }
    const v2f zz = {0.0f, 0.0f};
    v2f h1v[8];
    #pragma unroll
    for (int j = 0; j < 8; ++j) h1v[j] = __builtin_elementwise_max(a[j], zz);

    #pragma unroll
    for (int j = 0; j < 8; ++j) a[j] = (v2f){0.0f, 0.0f};
    #pragma unroll
    for (int i2 = 0; i2 < 8; ++i2) {
        const float h0 = h1v[i2].x;
        const float h1 = h1v[i2].y;
        const float4* w0 = reinterpret_cast<const float4*>(&sW1t[(2 * i2) * 16]);
        const float4* w1 = reinterpret_cast<const float4*>(&sW1t[(2 * i2 + 1) * 16]);
        #pragma unroll
        for (int q = 0; q < 4; ++q) {
            const float4 wa = w0[q];
            const float4 wb = w1[q];
            a[2 * q]     += h0 * (v2f){wa.x, wa.y} + h1 * (v2f){wb.x, wb.y};
            a[2 * q + 1] += h0 * (v2f){wa.z, wa.w} + h1 * (v2f){wb.z, wb.w};
        }
    }

    v2f acco = {0.0f, 0.0f};
    #pragma unroll
    for (int j = 0; j < 8; ++j) {
        const v2f h2v = __builtin_elementwise_max(a[j], zz);
        acco += h2v * (v2f){sW2[2 * j], sW2[2 * j + 1]};
    }
    out[gid] = acco.x + acco.y;
}

extern "C" void kernel_launch(void* const* d_in, const int* in_sizes, int n_in,
                              void* d_out, int out_size, void* d_ws, size_t ws_size,
                              hipStream_t stream) {
    const float* x     = (const float*)d_in[0];
    const float* table = (const float*)d_in[1];
    const float* W0    = (const float*)d_in[2];
    const float* W1    = (const float*)d_in[3];
    const float* W2    = (const float*)d_in[4];
    float* out = (float*)d_out;

    const int N = in_sizes[0] / 3;

    EncParams ep;
    const double g = pow(4.0, 1.0 / 7.0);
    for (int l = 0; l < 8; ++l) {
        ep.scale[l] = (float)(8.0 * pow(g, (double)l) - 1.0);
    }

    const size_t rowsBytes = (size_t)NROWS_L * 4;            // 33,412
    const size_t cellsOff  = (rowsBytes + 255) & ~(size_t)255;  // 33,536 -> pad to 33,536? keep 16B align
    const size_t needBytes = cellsOff + (size_t)NCELLS_F * 32;

    const int blocks = (N + 255) / 256;
    if (ws_size >= needBytes) {
        unsigned int* rowsH = (unsigned int*)d_ws;
        uint4* cellsF = (uint4*)((char*)d_ws + cellsOff);
        hipLaunchKernelGGL(build_rows_h, dim3((NROWS_L + 255) / 256), dim3(256),
                           0, stream, table, rowsH);
        hipLaunchKernelGGL(build_cells_f, dim3((NCELLS_F + 255) / 256), dim3(256),
                           0, stream, table, cellsF);
        hipLaunchKernelGGL(sdf_main, dim3(blocks), dim3(256), 0, stream,
                           x, rowsH, cellsF, W0, W1, W2, out, N, ep);
    } else {
        hipLaunchKernelGGL(sdf_fused_fallback, dim3(blocks), dim3(256), 0, stream,
                           x, table, W0, W1, W2, out, N, ep);
    }
}